// Round 1
// baseline (343.436 us; speedup 1.0000x reference)
//
#include <hip/hip_runtime.h>
#include <hip/hip_bf16.h>

// ---------------- problem constants ----------------
#define T_TOK 2048
#define DM    2048
#define FF    1408
#define NE    8
#define MT_ROUTED 40          // padded routed slot capacity / 128 (4096 + 8*127 -> <=5120)
#define MT_TOTAL  56          // + 2048/128 shared-expert tiles
#define ROUTED_CAP 5120
#define NSLOT 7168

typedef unsigned short u16;
typedef __attribute__((ext_vector_type(4))) u16 u16x4;
typedef __attribute__((ext_vector_type(8))) short bf16x8;
typedef __attribute__((ext_vector_type(4))) float f32x4;

__device__ __forceinline__ u16 f2bf(float f) {
    unsigned u = __float_as_uint(f);
    unsigned r = (u + 0x7FFFu + ((u >> 16) & 1u)) >> 16;
    return (u16)r;
}

__device__ __forceinline__ void gll16(const void* g, void* l) {
    __builtin_amdgcn_global_load_lds((const __attribute__((address_space(1))) void*)g,
                                     (__attribute__((address_space(3))) void*)l, 16, 0, 0);
}

// ---------------- workspace layout (bytes) ----------------
constexpr size_t SZ_XB  = (size_t)T_TOK * DM * 2;      // x bf16
constexpr size_t SZ_WE  = (size_t)NE * DM * FF * 2;    // one routed weight set, bf16
constexpr size_t SZ_SW  = (size_t)DM * FF * 2;         // one shared weight, bf16
constexpr size_t SZ_H   = (size_t)NSLOT * FF * 2;      // h bf16
constexpr size_t SZ_DN  = (size_t)NSLOT * DM * 4;      // down partials fp32

constexpr size_t OFF_XB   = 0;
constexpr size_t OFF_WGT  = OFF_XB + SZ_XB;
constexpr size_t OFF_WUT  = OFF_WGT + SZ_WE;
constexpr size_t OFF_WDT  = OFF_WUT + SZ_WE;
constexpr size_t OFF_SWG  = OFF_WDT + SZ_WE;
constexpr size_t OFF_SWU  = OFF_SWG + SZ_SW;
constexpr size_t OFF_SWD  = OFF_SWU + SZ_SW;
constexpr size_t OFF_H    = OFF_SWD + SZ_SW;
constexpr size_t OFF_DN   = OFF_H + SZ_H;
constexpr size_t OFF_TID  = OFF_DN + SZ_DN;            // topk ids   [T,2] int
constexpr size_t OFF_TW   = OFF_TID + (size_t)T_TOK*2*4; // topk w   [T,2] f32
constexpr size_t OFF_PERM = OFF_TW  + (size_t)T_TOK*2*4; // slot->token [5120]
constexpr size_t OFF_SW_S = OFF_PERM + (size_t)ROUTED_CAP*4; // slot gate w [5120]
constexpr size_t OFF_TKS  = OFF_SW_S + (size_t)ROUTED_CAP*4; // (t,k)->slot [T*2]
constexpr size_t OFF_TE   = OFF_TKS + (size_t)T_TOK*2*4;     // tile -> expert [56]

// ---------------- conversion kernels ----------------
__global__ void cvtx_kernel(const float* __restrict__ src, u16* __restrict__ dst) {
    const int i = blockIdx.x * 256 + threadIdx.x;
    const float4 v = ((const float4*)src)[i];
    u16x4 o; o.x = f2bf(v.x); o.y = f2bf(v.y); o.z = f2bf(v.z); o.w = f2bf(v.w);
    ((u16x4*)dst)[i] = o;
}

// [R][C] fp32 -> [C][R] bf16, 64x64 tiles via LDS; batch along z
__global__ void tcvt64_kernel(const float* __restrict__ src, u16* __restrict__ dst, int R, int C) {
    __shared__ u16 tile[64][72];
    const size_t msz = (size_t)R * C;
    const float* s = src + (size_t)blockIdx.z * msz;
    u16* d = dst + (size_t)blockIdx.z * msz;
    const int r0 = blockIdx.y * 64, c0 = blockIdx.x * 64;
    const int tr = threadIdx.x >> 4, tc = (threadIdx.x & 15) * 4;
#pragma unroll
    for (int i = 0; i < 4; i++) {
        const int r = tr + i * 16;
        const float4 v = *(const float4*)(s + (size_t)(r0 + r) * C + (c0 + tc));
        tile[r][tc+0] = f2bf(v.x); tile[r][tc+1] = f2bf(v.y);
        tile[r][tc+2] = f2bf(v.z); tile[r][tc+3] = f2bf(v.w);
    }
    __syncthreads();
#pragma unroll
    for (int i = 0; i < 4; i++) {
        const int c = tr + i * 16;
        u16x4 o;
        o.x = tile[tc+0][c]; o.y = tile[tc+1][c]; o.z = tile[tc+2][c]; o.w = tile[tc+3][c];
        *(u16x4*)(d + (size_t)(c0 + c) * R + (r0 + tc)) = o;
    }
}

// ---------------- router: fp32 logits -> softmax -> top2 ----------------
__global__ void router_kernel(const float* __restrict__ x, const float* __restrict__ gw,
                              int* __restrict__ topk_id, float* __restrict__ topk_w) {
    const int wv = threadIdx.x >> 6, l = threadIdx.x & 63;
    const int t = blockIdx.x * 4 + wv;
    const float* xt = x + (size_t)t * DM;
    float acc[NE] = {0.f,0.f,0.f,0.f,0.f,0.f,0.f,0.f};
    for (int d = l * 4; d < DM; d += 256) {
        const float4 xv = *(const float4*)(xt + d);
#pragma unroll
        for (int e = 0; e < NE; e++) {
            const float4 w4 = *(const float4*)(gw + e * DM + d);
            acc[e] += xv.x * w4.x + xv.y * w4.y + xv.z * w4.z + xv.w * w4.w;
        }
    }
#pragma unroll
    for (int e = 0; e < NE; e++)
#pragma unroll
        for (int off = 32; off > 0; off >>= 1) acc[e] += __shfl_xor(acc[e], off, 64);
    if (l == 0) {
        float m = acc[0];
#pragma unroll
        for (int e = 1; e < NE; e++) m = fmaxf(m, acc[e]);
        float p[NE];
#pragma unroll
        for (int e = 0; e < NE; e++) p[e] = __expf(acc[e] - m);
        int i1 = 0; float b1 = p[0];
#pragma unroll
        for (int e = 1; e < NE; e++) if (p[e] > b1) { b1 = p[e]; i1 = e; }
        int i2 = -1; float b2 = -1.f;
#pragma unroll
        for (int e = 0; e < NE; e++) if (e != i1 && p[e] > b2) { b2 = p[e]; i2 = e; }
        const float s = b1 + b2;
        topk_id[2*t] = i1; topk_id[2*t+1] = i2;
        topk_w[2*t] = b1 / s; topk_w[2*t+1] = b2 / s;
    }
}

// ---------------- deterministic expert scan / permutation ----------------
__global__ void scan_kernel(const int* __restrict__ topk_id, const float* __restrict__ topk_w,
                            int* __restrict__ perm_token, float* __restrict__ slot_w,
                            int* __restrict__ tk_slot, int* __restrict__ tile_e) {
    const int e = blockIdx.x;
    const int tid = threadIdx.x;
    __shared__ int cnt[NE];
    __shared__ int tsum[256];
    int ids[16];
#pragma unroll
    for (int j = 0; j < 16; j++) ids[j] = topk_id[tid * 16 + j];
    if (tid < NE) cnt[tid] = 0;
    __syncthreads();
#pragma unroll
    for (int e2 = 0; e2 < NE; e2++) {
        int c = 0;
#pragma unroll
        for (int j = 0; j < 16; j++) c += (ids[j] == e2);
        if (c) atomicAdd(&cnt[e2], c);
    }
    int mySum = 0;
#pragma unroll
    for (int j = 0; j < 16; j++) mySum += (ids[j] == e);
    tsum[tid] = mySum;
    __syncthreads();
    if (tid == 0) { int run = 0; for (int i = 0; i < 256; i++) { int v = tsum[i]; tsum[i] = run; run += v; } }
    __syncthreads();
    int poff = 0;
#pragma unroll
    for (int e2 = 0; e2 < NE; e2++) { int p = (cnt[e2] + 127) & ~127; if (e2 < e) poff += p; }
    const int padded_e = (cnt[e] + 127) & ~127;
    int run = tsum[tid];
#pragma unroll
    for (int j = 0; j < 16; j++) {
        if (ids[j] == e) {
            const int i = tid * 16 + j;
            const int slot = poff + run;
            perm_token[slot] = i >> 1;
            slot_w[slot] = topk_w[i];
            tk_slot[i] = slot;
            run++;
        }
    }
    for (int r = cnt[e] + tid; r < padded_e; r += 256) { perm_token[poff + r] = 0; slot_w[poff + r] = 0.f; }
    if (tid == 0) for (int tt = poff >> 7; tt < (poff + padded_e) >> 7; tt++) tile_e[tt] = e;
    if (e == 0 && tid == 1) {
        int ptot = 0;
#pragma unroll
        for (int e2 = 0; e2 < NE; e2++) ptot += (cnt[e2] + 127) & ~127;
        for (int tt = ptot >> 7; tt < MT_ROUTED; tt++) tile_e[tt] = -1;
        for (int tt = MT_ROUTED; tt < MT_TOTAL; tt++) tile_e[tt] = 8;
    }
}

// ---------------- GEMM1: x(perm) @ [Wg|Wu] -> h = silu(g)*u*w ----------------
__global__ __launch_bounds__(256, 2)
void gemm1_kernel(const u16* __restrict__ xb,
                  const u16* __restrict__ wgT, const u16* __restrict__ wuT,
                  const u16* __restrict__ swgT, const u16* __restrict__ swuT,
                  const int* __restrict__ perm_token, const float* __restrict__ slot_w,
                  const int* __restrict__ tile_e, u16* __restrict__ hbuf) {
    const int mtile = blockIdx.y, ntile = blockIdx.x;
    const int e = tile_e[mtile];
    if (e < 0) return;
    __shared__ u16 lA[128 * 64], lBg[128 * 64], lBu[128 * 64];
    __shared__ int lTok[128];
    __shared__ float lW[128];
    const int tid = threadIdx.x, l = tid & 63, w = tid >> 6;
    const bool sh = (e == 8);
    const int slot_base = sh ? (ROUTED_CAP + (mtile - MT_ROUTED) * 128) : mtile * 128;
    if (tid < 128) {
        if (sh) { lTok[tid] = (mtile - MT_ROUTED) * 128 + tid; lW[tid] = 1.0f; }
        else {
            int tok = perm_token[slot_base + tid];
            lTok[tid] = (tok < 0) ? 0 : tok;
            lW[tid] = slot_w[slot_base + tid];
        }
    }
    __syncthreads();
    const u16* Bg = sh ? swgT : (wgT + (size_t)e * FF * DM);
    const u16* Bu = sh ? swuT : (wuT + (size_t)e * FF * DM);
    const int n0 = ntile * 128;
    const u16* aSrc[4]; const u16* bgSrc[4]; const u16* buSrc[4]; int ldsOff[4];
#pragma unroll
    for (int i = 0; i < 4; i++) {
        const int row = i * 32 + w * 8 + (l >> 3);
        const int ch = (l & 7) ^ (row & 7);
        ldsOff[i] = (i * 32 + w * 8) * 64;
        aSrc[i]  = xb + (size_t)lTok[row] * DM + ch * 8;
        bgSrc[i] = Bg + (size_t)(n0 + row) * DM + ch * 8;
        buSrc[i] = Bu + (size_t)(n0 + row) * DM + ch * 8;
    }
    f32x4 accg[4][4] = {}; f32x4 accu[4][4] = {};
    const int wm = (w >> 1) * 64, wn = (w & 1) * 64;
    for (int k0 = 0; k0 < DM; k0 += 64) {
        __syncthreads();
#pragma unroll
        for (int i = 0; i < 4; i++) {
            gll16(aSrc[i] + k0, lA + ldsOff[i]);
            gll16(bgSrc[i] + k0, lBg + ldsOff[i]);
            gll16(buSrc[i] + k0, lBu + ldsOff[i]);
        }
        __syncthreads();
#pragma unroll
        for (int kk = 0; kk < 64; kk += 32) {
            bf16x8 af[4], bgf[4], buf2[4];
#pragma unroll
            for (int mi = 0; mi < 4; mi++) {
                const int row = wm + mi * 16 + (l & 15);
                const int ch = ((kk >> 3) + (l >> 4)) ^ (row & 7);
                af[mi] = *(const bf16x8*)(lA + row * 64 + ch * 8);
            }
#pragma unroll
            for (int ni = 0; ni < 4; ni++) {
                const int row = wn + ni * 16 + (l & 15);
                const int ch = ((kk >> 3) + (l >> 4)) ^ (row & 7);
                bgf[ni]  = *(const bf16x8*)(lBg + row * 64 + ch * 8);
                buf2[ni] = *(const bf16x8*)(lBu + row * 64 + ch * 8);
            }
#pragma unroll
            for (int mi = 0; mi < 4; mi++)
#pragma unroll
                for (int ni = 0; ni < 4; ni++) {
                    accg[mi][ni] = __builtin_amdgcn_mfma_f32_16x16x32_bf16(af[mi], bgf[ni], accg[mi][ni], 0, 0, 0);
                    accu[mi][ni] = __builtin_amdgcn_mfma_f32_16x16x32_bf16(af[mi], buf2[ni], accu[mi][ni], 0, 0, 0);
                }
        }
    }
#pragma unroll
    for (int mi = 0; mi < 4; mi++) {
#pragma unroll
        for (int r = 0; r < 4; r++) {
            const int m = wm + mi * 16 + (l >> 4) * 4 + r;
            const float wgt = lW[m];
#pragma unroll
            for (int ni = 0; ni < 4; ni++) {
                const int n = wn + ni * 16 + (l & 15);
                const float g = accg[mi][ni][r], u = accu[mi][ni][r];
                const float h = g * (1.f / (1.f + __expf(-g))) * u * wgt;
                hbuf[(size_t)(slot_base + m) * FF + n0 + n] = f2bf(h);
            }
        }
    }
}

// ---------------- GEMM2: h @ Wd -> per-slot down partials (fp32) ----------------
__global__ __launch_bounds__(256, 2)
void gemm2_kernel(const u16* __restrict__ hbuf, const u16* __restrict__ wdT,
                  const u16* __restrict__ swdT, const int* __restrict__ tile_e,
                  float* __restrict__ dn) {
    const int mtile = blockIdx.y, ntile = blockIdx.x;
    const int e = tile_e[mtile];
    if (e < 0) return;
    __shared__ u16 lA[128 * 64], lB[128 * 64];
    const int tid = threadIdx.x, l = tid & 63, w = tid >> 6;
    const bool sh = (e == 8);
    const int slot_base = sh ? (ROUTED_CAP + (mtile - MT_ROUTED) * 128) : mtile * 128;
    const u16* Bp = sh ? swdT : (wdT + (size_t)e * DM * FF);
    const int n0 = ntile * 128;
    const u16* aSrc[4]; const u16* bSrc[4]; int ldsOff[4];
#pragma unroll
    for (int i = 0; i < 4; i++) {
        const int row = i * 32 + w * 8 + (l >> 3);
        const int ch = (l & 7) ^ (row & 7);
        ldsOff[i] = (i * 32 + w * 8) * 64;
        aSrc[i] = hbuf + (size_t)(slot_base + row) * FF + ch * 8;
        bSrc[i] = Bp + (size_t)(n0 + row) * FF + ch * 8;
    }
    f32x4 acc[4][4] = {};
    const int wm = (w >> 1) * 64, wn = (w & 1) * 64;
    for (int k0 = 0; k0 < FF; k0 += 64) {
        __syncthreads();
#pragma unroll
        for (int i = 0; i < 4; i++) { gll16(aSrc[i] + k0, lA + ldsOff[i]); gll16(bSrc[i] + k0, lB + ldsOff[i]); }
        __syncthreads();
#pragma unroll
        for (int kk = 0; kk < 64; kk += 32) {
            bf16x8 af[4], bf_[4];
#pragma unroll
            for (int mi = 0; mi < 4; mi++) {
                const int row = wm + mi * 16 + (l & 15);
                const int ch = ((kk >> 3) + (l >> 4)) ^ (row & 7);
                af[mi] = *(const bf16x8*)(lA + row * 64 + ch * 8);
            }
#pragma unroll
            for (int ni = 0; ni < 4; ni++) {
                const int row = wn + ni * 16 + (l & 15);
                const int ch = ((kk >> 3) + (l >> 4)) ^ (row & 7);
                bf_[ni] = *(const bf16x8*)(lB + row * 64 + ch * 8);
            }
#pragma unroll
            for (int mi = 0; mi < 4; mi++)
#pragma unroll
                for (int ni = 0; ni < 4; ni++)
                    acc[mi][ni] = __builtin_amdgcn_mfma_f32_16x16x32_bf16(af[mi], bf_[ni], acc[mi][ni], 0, 0, 0);
        }
    }
#pragma unroll
    for (int mi = 0; mi < 4; mi++)
#pragma unroll
        for (int r = 0; r < 4; r++) {
            const int m = wm + mi * 16 + (l >> 4) * 4 + r;
#pragma unroll
            for (int ni = 0; ni < 4; ni++) {
                const int n = wn + ni * 16 + (l & 15);
                dn[(size_t)(slot_base + m) * DM + n0 + n] = acc[mi][ni][r];
            }
        }
}

// ---------------- combine: out[t] = dn[s1] + dn[s2] + dn[shared] ----------------
__global__ void combine_kernel(const float* __restrict__ dn, const int* __restrict__ tk_slot,
                               float* __restrict__ out) {
    const int i = blockIdx.x * 256 + threadIdx.x;
    const int base = i * 4;
    const int t = base >> 11, d = base & 2047;
    const int s1 = tk_slot[2 * t], s2 = tk_slot[2 * t + 1];
    const float4 a = *(const float4*)(dn + (size_t)s1 * DM + d);
    const float4 b = *(const float4*)(dn + (size_t)s2 * DM + d);
    const float4 c = *(const float4*)(dn + (size_t)(ROUTED_CAP + t) * DM + d);
    float4 o;
    o.x = a.x + b.x + c.x; o.y = a.y + b.y + c.y;
    o.z = a.z + b.z + c.z; o.w = a.w + b.w + c.w;
    *(float4*)(out + base) = o;
}

// ---------------- launch ----------------
extern "C" void kernel_launch(void* const* d_in, const int* in_sizes, int n_in,
                              void* d_out, int out_size, void* d_ws, size_t ws_size,
                              hipStream_t stream) {
    (void)in_sizes; (void)n_in; (void)out_size; (void)ws_size;
    const float* x   = (const float*)d_in[0];
    const float* gw  = (const float*)d_in[1];
    const float* wg  = (const float*)d_in[2];
    const float* wu  = (const float*)d_in[3];
    const float* wd  = (const float*)d_in[4];
    const float* swg = (const float*)d_in[5];
    const float* swu = (const float*)d_in[6];
    const float* swd = (const float*)d_in[7];
    float* out = (float*)d_out;
    char* ws = (char*)d_ws;

    u16*   xb    = (u16*)(ws + OFF_XB);
    u16*   wgT   = (u16*)(ws + OFF_WGT);
    u16*   wuT   = (u16*)(ws + OFF_WUT);
    u16*   wdT   = (u16*)(ws + OFF_WDT);
    u16*   swgT  = (u16*)(ws + OFF_SWG);
    u16*   swuT  = (u16*)(ws + OFF_SWU);
    u16*   swdT  = (u16*)(ws + OFF_SWD);
    u16*   hbuf  = (u16*)(ws + OFF_H);
    float* dn    = (float*)(ws + OFF_DN);
    int*   tid_  = (int*)(ws + OFF_TID);
    float* tw    = (float*)(ws + OFF_TW);
    int*   perm  = (int*)(ws + OFF_PERM);
    float* slw   = (float*)(ws + OFF_SW_S);
    int*   tks   = (int*)(ws + OFF_TKS);
    int*   te    = (int*)(ws + OFF_TE);

    // conversions
    cvtx_kernel<<<(T_TOK * DM / 4) / 256, 256, 0, stream>>>(x, xb);
    tcvt64_kernel<<<dim3(FF / 64, DM / 64, NE), 256, 0, stream>>>(wg, wgT, DM, FF);
    tcvt64_kernel<<<dim3(FF / 64, DM / 64, NE), 256, 0, stream>>>(wu, wuT, DM, FF);
    tcvt64_kernel<<<dim3(DM / 64, FF / 64, NE), 256, 0, stream>>>(wd, wdT, FF, DM);
    tcvt64_kernel<<<dim3(FF / 64, DM / 64, 1), 256, 0, stream>>>(swg, swgT, DM, FF);
    tcvt64_kernel<<<dim3(FF / 64, DM / 64, 1), 256, 0, stream>>>(swu, swuT, DM, FF);
    tcvt64_kernel<<<dim3(DM / 64, FF / 64, 1), 256, 0, stream>>>(swd, swdT, FF, DM);
    // routing
    router_kernel<<<T_TOK / 4, 256, 0, stream>>>(x, gw, tid_, tw);
    scan_kernel<<<NE, 256, 0, stream>>>(tid_, tw, perm, slw, tks, te);
    // expert GEMMs
    gemm1_kernel<<<dim3(FF / 128, MT_TOTAL), 256, 0, stream>>>(xb, wgT, wuT, swgT, swuT, perm, slw, te, hbuf);
    gemm2_kernel<<<dim3(DM / 128, MT_TOTAL), 256, 0, stream>>>(hbuf, wdT, swdT, te, dn);
    // combine
    combine_kernel<<<(T_TOK * DM / 4) / 256, 256, 0, stream>>>(dn, tks, out);
}

// Round 2
// 293.427 us; speedup vs baseline: 1.1704x; 1.1704x over previous
//
#include <hip/hip_runtime.h>
#include <hip/hip_bf16.h>

// ---------------- problem constants ----------------
#define T_TOK 2048
#define DM    2048
#define FF    1408
#define NE    8
#define MT_ROUTED 40          // padded routed slot capacity / 128
#define MT_TOTAL  56          // + 2048/128 shared-expert tiles
#define ROUTED_CAP 5120
#define NSLOT 7168

typedef unsigned short u16;
typedef __attribute__((ext_vector_type(4))) u16 u16x4;
typedef __attribute__((ext_vector_type(8))) short bf16x8;
typedef __attribute__((ext_vector_type(4))) float f32x4;

__device__ __forceinline__ u16 f2bf(float f) {
    unsigned u = __float_as_uint(f);
    unsigned r = (u + 0x7FFFu + ((u >> 16) & 1u)) >> 16;
    return (u16)r;
}
__device__ __forceinline__ float bf2f(u16 v) {
    return __uint_as_float(((unsigned)v) << 16);
}

__device__ __forceinline__ void gll16(const void* g, void* l) {
    __builtin_amdgcn_global_load_lds((const __attribute__((address_space(1))) void*)g,
                                     (__attribute__((address_space(3))) void*)l, 16, 0, 0);
}

// ---------------- workspace layout (bytes) ----------------
constexpr size_t SZ_XB  = (size_t)T_TOK * DM * 2;      // x bf16
constexpr size_t SZ_WE  = (size_t)NE * DM * FF * 2;    // one routed weight set, bf16
constexpr size_t SZ_SW  = (size_t)DM * FF * 2;         // one shared weight, bf16
constexpr size_t SZ_H   = (size_t)NSLOT * FF * 2;      // h bf16
constexpr size_t SZ_DN  = (size_t)NSLOT * DM * 2;      // down partials bf16

constexpr size_t OFF_XB   = 0;
constexpr size_t OFF_WGT  = OFF_XB + SZ_XB;
constexpr size_t OFF_WUT  = OFF_WGT + SZ_WE;
constexpr size_t OFF_WDT  = OFF_WUT + SZ_WE;
constexpr size_t OFF_SWG  = OFF_WDT + SZ_WE;
constexpr size_t OFF_SWU  = OFF_SWG + SZ_SW;
constexpr size_t OFF_SWD  = OFF_SWU + SZ_SW;
constexpr size_t OFF_H    = OFF_SWD + SZ_SW;
constexpr size_t OFF_DN   = OFF_H + SZ_H;
constexpr size_t OFF_TID  = OFF_DN + SZ_DN;              // topk ids   [T,2] int
constexpr size_t OFF_TW   = OFF_TID + (size_t)T_TOK*2*4; // topk w     [T,2] f32
constexpr size_t OFF_PERM = OFF_TW  + (size_t)T_TOK*2*4; // slot->token
constexpr size_t OFF_SW_S = OFF_PERM + (size_t)ROUTED_CAP*4; // slot gate w
constexpr size_t OFF_TKS  = OFF_SW_S + (size_t)ROUTED_CAP*4; // (t,k)->slot
constexpr size_t OFF_TE   = OFF_TKS + (size_t)T_TOK*2*4;     // tile -> expert

// ---------------- batched transpose-convert ----------------
// group A: [DM][FF] fp32 -> [FF][DM] bf16 ; z<8: wg, z<16: wu, 16: swg, 17: swu
__global__ void tcvtA_kernel(const float* __restrict__ wg, const float* __restrict__ wu,
                             const float* __restrict__ swg, const float* __restrict__ swu,
                             u16* __restrict__ wgT, u16* __restrict__ wuT,
                             u16* __restrict__ swgT, u16* __restrict__ swuT) {
    __shared__ u16 tile[64][72];
    const int z = blockIdx.z;
    const size_t msz = (size_t)DM * FF;
    const float* s; u16* d;
    if (z < 8)       { s = wg + (size_t)z * msz;        d = wgT + (size_t)z * msz; }
    else if (z < 16) { s = wu + (size_t)(z - 8) * msz;  d = wuT + (size_t)(z - 8) * msz; }
    else if (z == 16){ s = swg;                          d = swgT; }
    else             { s = swu;                          d = swuT; }
    const int R = DM, C = FF;
    const int r0 = blockIdx.y * 64, c0 = blockIdx.x * 64;
    const int tr = threadIdx.x >> 4, tc = (threadIdx.x & 15) * 4;
#pragma unroll
    for (int i = 0; i < 4; i++) {
        const int r = tr + i * 16;
        const float4 v = *(const float4*)(s + (size_t)(r0 + r) * C + (c0 + tc));
        tile[r][tc+0] = f2bf(v.x); tile[r][tc+1] = f2bf(v.y);
        tile[r][tc+2] = f2bf(v.z); tile[r][tc+3] = f2bf(v.w);
    }
    __syncthreads();
#pragma unroll
    for (int i = 0; i < 4; i++) {
        const int c = tr + i * 16;
        u16x4 o;
        o.x = tile[tc+0][c]; o.y = tile[tc+1][c]; o.z = tile[tc+2][c]; o.w = tile[tc+3][c];
        *(u16x4*)(d + (size_t)(c0 + c) * R + (r0 + tc)) = o;
    }
}

// group B: [FF][DM] fp32 -> [DM][FF] bf16 ; z<8: wd, z==8: swd
__global__ void tcvtB_kernel(const float* __restrict__ wd, const float* __restrict__ swd,
                             u16* __restrict__ wdT, u16* __restrict__ swdT) {
    __shared__ u16 tile[64][72];
    const int z = blockIdx.z;
    const size_t msz = (size_t)DM * FF;
    const float* s; u16* d;
    if (z < 8) { s = wd + (size_t)z * msz; d = wdT + (size_t)z * msz; }
    else       { s = swd;                  d = swdT; }
    const int R = FF, C = DM;
    const int r0 = blockIdx.y * 64, c0 = blockIdx.x * 64;
    const int tr = threadIdx.x >> 4, tc = (threadIdx.x & 15) * 4;
#pragma unroll
    for (int i = 0; i < 4; i++) {
        const int r = tr + i * 16;
        const float4 v = *(const float4*)(s + (size_t)(r0 + r) * C + (c0 + tc));
        tile[r][tc+0] = f2bf(v.x); tile[r][tc+1] = f2bf(v.y);
        tile[r][tc+2] = f2bf(v.z); tile[r][tc+3] = f2bf(v.w);
    }
    __syncthreads();
#pragma unroll
    for (int i = 0; i < 4; i++) {
        const int c = tr + i * 16;
        u16x4 o;
        o.x = tile[tc+0][c]; o.y = tile[tc+1][c]; o.z = tile[tc+2][c]; o.w = tile[tc+3][c];
        *(u16x4*)(d + (size_t)(c0 + c) * R + (r0 + tc)) = o;
    }
}

// ---------------- router (+ fused x -> bf16 convert) ----------------
__global__ void router_kernel(const float* __restrict__ x, const float* __restrict__ gw,
                              u16* __restrict__ xb,
                              int* __restrict__ topk_id, float* __restrict__ topk_w) {
    const int wv = threadIdx.x >> 6, l = threadIdx.x & 63;
    const int t = blockIdx.x * 4 + wv;
    const float* xt = x + (size_t)t * DM;
    u16* xbt = xb + (size_t)t * DM;
    float acc[NE] = {0.f,0.f,0.f,0.f,0.f,0.f,0.f,0.f};
    for (int d = l * 4; d < DM; d += 256) {
        const float4 xv = *(const float4*)(xt + d);
        u16x4 o; o.x = f2bf(xv.x); o.y = f2bf(xv.y); o.z = f2bf(xv.z); o.w = f2bf(xv.w);
        *(u16x4*)(xbt + d) = o;
#pragma unroll
        for (int e = 0; e < NE; e++) {
            const float4 w4 = *(const float4*)(gw + e * DM + d);
            acc[e] += xv.x * w4.x + xv.y * w4.y + xv.z * w4.z + xv.w * w4.w;
        }
    }
#pragma unroll
    for (int e = 0; e < NE; e++)
#pragma unroll
        for (int off = 32; off > 0; off >>= 1) acc[e] += __shfl_xor(acc[e], off, 64);
    if (l == 0) {
        float m = acc[0];
#pragma unroll
        for (int e = 1; e < NE; e++) m = fmaxf(m, acc[e]);
        float p[NE];
#pragma unroll
        for (int e = 0; e < NE; e++) p[e] = __expf(acc[e] - m);
        int i1 = 0; float b1 = p[0];
#pragma unroll
        for (int e = 1; e < NE; e++) if (p[e] > b1) { b1 = p[e]; i1 = e; }
        int i2 = -1; float b2 = -1.f;
#pragma unroll
        for (int e = 0; e < NE; e++) if (e != i1 && p[e] > b2) { b2 = p[e]; i2 = e; }
        const float s = b1 + b2;
        topk_id[2*t] = i1; topk_id[2*t+1] = i2;
        topk_w[2*t] = b1 / s; topk_w[2*t+1] = b2 / s;
    }
}

// ---------------- deterministic expert scan / permutation ----------------
__global__ void scan_kernel(const int* __restrict__ topk_id, const float* __restrict__ topk_w,
                            int* __restrict__ perm_token, float* __restrict__ slot_w,
                            int* __restrict__ tk_slot, int* __restrict__ tile_e) {
    const int e = blockIdx.x;
    const int tid = threadIdx.x;
    __shared__ int cnt[NE];
    __shared__ int tsum[256];
    int ids[16];
#pragma unroll
    for (int j = 0; j < 16; j++) ids[j] = topk_id[tid * 16 + j];
    if (tid < NE) cnt[tid] = 0;
    __syncthreads();
#pragma unroll
    for (int e2 = 0; e2 < NE; e2++) {
        int c = 0;
#pragma unroll
        for (int j = 0; j < 16; j++) c += (ids[j] == e2);
        if (c) atomicAdd(&cnt[e2], c);
    }
    int mySum = 0;
#pragma unroll
    for (int j = 0; j < 16; j++) mySum += (ids[j] == e);
    tsum[tid] = mySum;
    __syncthreads();
    if (tid == 0) { int run = 0; for (int i = 0; i < 256; i++) { int v = tsum[i]; tsum[i] = run; run += v; } }
    __syncthreads();
    int poff = 0;
#pragma unroll
    for (int e2 = 0; e2 < NE; e2++) { int p = (cnt[e2] + 127) & ~127; if (e2 < e) poff += p; }
    const int padded_e = (cnt[e] + 127) & ~127;
    int run = tsum[tid];
#pragma unroll
    for (int j = 0; j < 16; j++) {
        if (ids[j] == e) {
            const int i = tid * 16 + j;
            const int slot = poff + run;
            perm_token[slot] = i >> 1;
            slot_w[slot] = topk_w[i];
            tk_slot[i] = slot;
            run++;
        }
    }
    for (int r = cnt[e] + tid; r < padded_e; r += 256) { perm_token[poff + r] = 0; slot_w[poff + r] = 0.f; }
    if (tid == 0) for (int tt = poff >> 7; tt < (poff + padded_e) >> 7; tt++) tile_e[tt] = e;
    if (e == 0 && tid == 1) {
        int ptot = 0;
#pragma unroll
        for (int e2 = 0; e2 < NE; e2++) ptot += (cnt[e2] + 127) & ~127;
        for (int tt = ptot >> 7; tt < MT_ROUTED; tt++) tile_e[tt] = -1;
        for (int tt = MT_ROUTED; tt < MT_TOTAL; tt++) tile_e[tt] = 8;
    }
}

// ---------------- GEMM1: 128xM x 64xN, B-tile = [gate 64 | up 64] rows ----------------
__global__ __launch_bounds__(256, 3)
void gemm1_kernel(const u16* __restrict__ xb,
                  const u16* __restrict__ wgT, const u16* __restrict__ wuT,
                  const u16* __restrict__ swgT, const u16* __restrict__ swuT,
                  const int* __restrict__ perm_token, const float* __restrict__ slot_w,
                  const int* __restrict__ tile_e, u16* __restrict__ hbuf) {
    const int mtile = blockIdx.y, ntile = blockIdx.x;   // ntile over FF/64 = 22
    const int e = tile_e[mtile];
    if (e < 0) return;
    __shared__ u16 lA[128 * 64], lB[128 * 64];
    __shared__ int lTok[128];
    __shared__ float lW[128];
    const int tid = threadIdx.x, l = tid & 63, w = tid >> 6;
    const bool sh = (e == 8);
    const int slot_base = sh ? (ROUTED_CAP + (mtile - MT_ROUTED) * 128) : mtile * 128;
    if (tid < 128) {
        if (sh) { lTok[tid] = (mtile - MT_ROUTED) * 128 + tid; lW[tid] = 1.0f; }
        else {
            int tok = perm_token[slot_base + tid];
            lTok[tid] = (tok < 0) ? 0 : tok;
            lW[tid] = slot_w[slot_base + tid];
        }
    }
    __syncthreads();
    const u16* Bg = sh ? swgT : (wgT + (size_t)e * FF * DM);
    const u16* Bu = sh ? swuT : (wuT + (size_t)e * FF * DM);
    const int n0 = ntile * 64;
    const u16* aSrc[4]; const u16* bSrc[4]; int ldsOff[4];
#pragma unroll
    for (int i = 0; i < 4; i++) {
        const int row = i * 32 + w * 8 + (l >> 3);
        const int ch = (l & 7) ^ (row & 7);
        ldsOff[i] = (i * 32 + w * 8) * 64;
        aSrc[i] = xb + (size_t)lTok[row] * DM + ch * 8;
        // B rows 0..63 -> gate col (n0+row); rows 64..127 -> up col (n0+row-64)
        const u16* bbase = (i < 2) ? (Bg + (size_t)(n0 + row) * DM)
                                   : (Bu + (size_t)(n0 + row - 64) * DM);
        bSrc[i] = bbase + ch * 8;
    }
    f32x4 acc[2][8] = {};
    const int wm = w * 32;
    for (int k0 = 0; k0 < DM; k0 += 64) {
        __syncthreads();
#pragma unroll
        for (int i = 0; i < 4; i++) { gll16(aSrc[i] + k0, lA + ldsOff[i]); gll16(bSrc[i] + k0, lB + ldsOff[i]); }
        __syncthreads();
#pragma unroll
        for (int kk = 0; kk < 64; kk += 32) {
            bf16x8 af[2], bf_[8];
#pragma unroll
            for (int mi = 0; mi < 2; mi++) {
                const int row = wm + mi * 16 + (l & 15);
                const int ch = ((kk >> 3) + (l >> 4)) ^ (row & 7);
                af[mi] = *(const bf16x8*)(lA + row * 64 + ch * 8);
            }
#pragma unroll
            for (int ni = 0; ni < 8; ni++) {
                const int row = ni * 16 + (l & 15);
                const int ch = ((kk >> 3) + (l >> 4)) ^ (row & 7);
                bf_[ni] = *(const bf16x8*)(lB + row * 64 + ch * 8);
            }
#pragma unroll
            for (int mi = 0; mi < 2; mi++)
#pragma unroll
                for (int ni = 0; ni < 8; ni++)
                    acc[mi][ni] = __builtin_amdgcn_mfma_f32_16x16x32_bf16(af[mi], bf_[ni], acc[mi][ni], 0, 0, 0);
        }
    }
#pragma unroll
    for (int mi = 0; mi < 2; mi++)
#pragma unroll
        for (int r = 0; r < 4; r++) {
            const int m = wm + mi * 16 + (l >> 4) * 4 + r;
            const float wgt = lW[m];
#pragma unroll
            for (int ni = 0; ni < 4; ni++) {
                const int n = ni * 16 + (l & 15);
                const float g = acc[mi][ni][r], u = acc[mi][ni + 4][r];
                const float h = g * (1.f / (1.f + __expf(-g))) * u * wgt;
                hbuf[(size_t)(slot_base + m) * FF + n0 + n] = f2bf(h);
            }
        }
}

// ---------------- GEMM2: 128xM x 64xN, h @ Wd -> dn (bf16) ----------------
__global__ __launch_bounds__(256, 4)
void gemm2_kernel(const u16* __restrict__ hbuf, const u16* __restrict__ wdT,
                  const u16* __restrict__ swdT, const int* __restrict__ tile_e,
                  u16* __restrict__ dn) {
    const int mtile = blockIdx.y, ntile = blockIdx.x;   // ntile over DM/64 = 32
    const int e = tile_e[mtile];
    if (e < 0) return;
    __shared__ u16 lA[128 * 64], lB[64 * 64];
    const int tid = threadIdx.x, l = tid & 63, w = tid >> 6;
    const bool sh = (e == 8);
    const int slot_base = sh ? (ROUTED_CAP + (mtile - MT_ROUTED) * 128) : mtile * 128;
    const u16* Bp = sh ? swdT : (wdT + (size_t)e * DM * FF);
    const int n0 = ntile * 64;
    const u16* aSrc[4]; const u16* bSrc[2]; int ldsOffA[4]; int ldsOffB[2];
#pragma unroll
    for (int i = 0; i < 4; i++) {
        const int row = i * 32 + w * 8 + (l >> 3);
        const int ch = (l & 7) ^ (row & 7);
        ldsOffA[i] = (i * 32 + w * 8) * 64;
        aSrc[i] = hbuf + (size_t)(slot_base + row) * FF + ch * 8;
    }
#pragma unroll
    for (int i = 0; i < 2; i++) {
        const int row = i * 32 + w * 8 + (l >> 3);
        const int ch = (l & 7) ^ (row & 7);
        ldsOffB[i] = (i * 32 + w * 8) * 64;
        bSrc[i] = Bp + (size_t)(n0 + row) * FF + ch * 8;
    }
    f32x4 acc[2][4] = {};
    const int wm = w * 32;
    for (int k0 = 0; k0 < FF; k0 += 64) {
        __syncthreads();
#pragma unroll
        for (int i = 0; i < 4; i++) gll16(aSrc[i] + k0, lA + ldsOffA[i]);
#pragma unroll
        for (int i = 0; i < 2; i++) gll16(bSrc[i] + k0, lB + ldsOffB[i]);
        __syncthreads();
#pragma unroll
        for (int kk = 0; kk < 64; kk += 32) {
            bf16x8 af[2], bf_[4];
#pragma unroll
            for (int mi = 0; mi < 2; mi++) {
                const int row = wm + mi * 16 + (l & 15);
                const int ch = ((kk >> 3) + (l >> 4)) ^ (row & 7);
                af[mi] = *(const bf16x8*)(lA + row * 64 + ch * 8);
            }
#pragma unroll
            for (int ni = 0; ni < 4; ni++) {
                const int row = ni * 16 + (l & 15);
                const int ch = ((kk >> 3) + (l >> 4)) ^ (row & 7);
                bf_[ni] = *(const bf16x8*)(lB + row * 64 + ch * 8);
            }
#pragma unroll
            for (int mi = 0; mi < 2; mi++)
#pragma unroll
                for (int ni = 0; ni < 4; ni++)
                    acc[mi][ni] = __builtin_amdgcn_mfma_f32_16x16x32_bf16(af[mi], bf_[ni], acc[mi][ni], 0, 0, 0);
        }
    }
#pragma unroll
    for (int mi = 0; mi < 2; mi++)
#pragma unroll
        for (int r = 0; r < 4; r++) {
            const int m = wm + mi * 16 + (l >> 4) * 4 + r;
#pragma unroll
            for (int ni = 0; ni < 4; ni++) {
                const int n = ni * 16 + (l & 15);
                dn[(size_t)(slot_base + m) * DM + n0 + n] = f2bf(acc[mi][ni][r]);
            }
        }
}

// ---------------- combine: out[t] = dn[s1] + dn[s2] + dn[shared] ----------------
__global__ void combine_kernel(const u16* __restrict__ dn, const int* __restrict__ tk_slot,
                               float* __restrict__ out) {
    const int i = blockIdx.x * 256 + threadIdx.x;
    const int base = i * 8;
    const int t = base >> 11, d = base & 2047;
    const int s1 = tk_slot[2 * t], s2 = tk_slot[2 * t + 1];
    const bf16x8 a = *(const bf16x8*)(dn + (size_t)s1 * DM + d);
    const bf16x8 b = *(const bf16x8*)(dn + (size_t)s2 * DM + d);
    const bf16x8 c = *(const bf16x8*)(dn + (size_t)(ROUTED_CAP + t) * DM + d);
    float o[8];
#pragma unroll
    for (int j = 0; j < 8; j++)
        o[j] = bf2f((u16)a[j]) + bf2f((u16)b[j]) + bf2f((u16)c[j]);
    float4 lo, hi;
    lo.x = o[0]; lo.y = o[1]; lo.z = o[2]; lo.w = o[3];
    hi.x = o[4]; hi.y = o[5]; hi.z = o[6]; hi.w = o[7];
    *(float4*)(out + base) = lo;
    *(float4*)(out + base + 4) = hi;
}

// ---------------- launch ----------------
extern "C" void kernel_launch(void* const* d_in, const int* in_sizes, int n_in,
                              void* d_out, int out_size, void* d_ws, size_t ws_size,
                              hipStream_t stream) {
    (void)in_sizes; (void)n_in; (void)out_size; (void)ws_size;
    const float* x   = (const float*)d_in[0];
    const float* gw  = (const float*)d_in[1];
    const float* wg  = (const float*)d_in[2];
    const float* wu  = (const float*)d_in[3];
    const float* wd  = (const float*)d_in[4];
    const float* swg = (const float*)d_in[5];
    const float* swu = (const float*)d_in[6];
    const float* swd = (const float*)d_in[7];
    float* out = (float*)d_out;
    char* ws = (char*)d_ws;

    u16*   xb    = (u16*)(ws + OFF_XB);
    u16*   wgT   = (u16*)(ws + OFF_WGT);
    u16*   wuT   = (u16*)(ws + OFF_WUT);
    u16*   wdT   = (u16*)(ws + OFF_WDT);
    u16*   swgT  = (u16*)(ws + OFF_SWG);
    u16*   swuT  = (u16*)(ws + OFF_SWU);
    u16*   swdT  = (u16*)(ws + OFF_SWD);
    u16*   hbuf  = (u16*)(ws + OFF_H);
    u16*   dn    = (u16*)(ws + OFF_DN);
    int*   tid_  = (int*)(ws + OFF_TID);
    float* tw    = (float*)(ws + OFF_TW);
    int*   perm  = (int*)(ws + OFF_PERM);
    float* slw   = (float*)(ws + OFF_SW_S);
    int*   tks   = (int*)(ws + OFF_TKS);
    int*   te    = (int*)(ws + OFF_TE);

    // routing (+x convert) and conversions
    router_kernel<<<T_TOK / 4, 256, 0, stream>>>(x, gw, xb, tid_, tw);
    scan_kernel<<<NE, 256, 0, stream>>>(tid_, tw, perm, slw, tks, te);
    tcvtA_kernel<<<dim3(FF / 64, DM / 64, 18), 256, 0, stream>>>(wg, wu, swg, swu, wgT, wuT, swgT, swuT);
    tcvtB_kernel<<<dim3(DM / 64, FF / 64, 9), 256, 0, stream>>>(wd, swd, wdT, swdT);
    // expert GEMMs
    gemm1_kernel<<<dim3(FF / 64, MT_TOTAL), 256, 0, stream>>>(xb, wgT, wuT, swgT, swuT, perm, slw, te, hbuf);
    gemm2_kernel<<<dim3(DM / 64, MT_TOTAL), 256, 0, stream>>>(hbuf, wdT, swdT, te, dn);
    // combine
    combine_kernel<<<(T_TOK * DM / 8) / 256, 256, 0, stream>>>(dn, tks, out);
}